// Round 3
// baseline (287.641 us; speedup 1.0000x reference)
//
#include <hip/hip_runtime.h>
#include <hip/hip_bf16.h>

// TopKPool: B=128, K=512, D=768, topk=8 (derived from in_sizes at launch).
// Outputs (concatenated fp32): pooled (B,D), attn_weights (B,K).

#define TKP_NEG_INF  (-1e30f)
#define TKP_FLT_LOW  (-3.402823466e38f)
#define TKP_MAXK     2048   // max sequence length supported by select kernel
#define TKP_MAXSEL   512    // max topk supported

// ---------------- Kernel 1: masked linear scores ----------------
// Specialized on D4 = D/4 so the load loop fully unrolls (12 independent
// float4 loads in flight per lane at D=768). 16-lane groups: one row per
// group -> 4-step shuffle reduce. Wave reads 4 rows' 256B segments, all
// cache-line aligned and fully consumed.
template<int D4>
__global__ __launch_bounds__(256) void topkpool_scores_t(
    const float* __restrict__ emb, const int* __restrict__ mask,
    const float* __restrict__ w, const float* __restrict__ bias,
    float* __restrict__ scores, int rows)
{
    const int g = threadIdx.x >> 4;        // 16 groups per block
    const int l = threadIdx.x & 15;
    const int r = blockIdx.x * 16 + g;     // one row per 16-lane group
    if (r >= rows) return;

    const float4* __restrict__ e4 = reinterpret_cast<const float4*>(emb) + (size_t)r * D4;
    const float4* __restrict__ w4 = reinterpret_cast<const float4*>(w);

    float sum = 0.f;
    #pragma unroll
    for (int i = 0; i < D4 / 16; ++i) {
        const int p = i * 16 + l;
        float4 a = e4[p];
        float4 b = w4[p];
        sum += a.x * b.x + a.y * b.y + a.z * b.z + a.w * b.w;
    }
    // residue (D4 not multiple of 16) — dead code for D4=192
    for (int p = (D4 / 16) * 16 + l; p < D4; p += 16) {
        float4 a = e4[p]; float4 b = w4[p];
        sum += a.x * b.x + a.y * b.y + a.z * b.z + a.w * b.w;
    }
    #pragma unroll
    for (int off = 8; off; off >>= 1) sum += __shfl_xor(sum, off, 64);

    if (l == 0) {
        float s = sum + bias[0];
        if (mask[r] == 0) s = TKP_NEG_INF;
        scores[r] = s;
    }
}

// Generic fallback (any D): one 64-lane wave per row.
__global__ __launch_bounds__(256) void topkpool_scores_gen(
    const float* __restrict__ emb, const int* __restrict__ mask,
    const float* __restrict__ w, const float* __restrict__ bias,
    float* __restrict__ scores, int rows, int D)
{
    const int wave = threadIdx.x >> 6;
    const int lane = threadIdx.x & 63;
    const int r = blockIdx.x * 4 + wave;
    if (r >= rows) return;
    const float* __restrict__ e = emb + (size_t)r * D;
    float sum = 0.f;
    for (int p = lane; p < D; p += 64) sum += e[p] * w[p];
    #pragma unroll
    for (int off = 32; off; off >>= 1) sum += __shfl_xor(sum, off, 64);
    if (lane == 0) {
        float s = sum + bias[0];
        if (mask[r] == 0) s = TKP_NEG_INF;
        scores[r] = s;
    }
}

// ---------------- Kernel 2: top-k select + pool + attn weights ----------------
// One block (256 threads) per batch row. Wave 0 runs the entire k-round
// argmax with shuffle butterflies (NO barriers in the loop); waves 1-3
// concurrently zero the attn row. ONE __syncthreads, then all threads
// pool (float4) and scatter 1/k.
__global__ __launch_bounds__(256) void topkpool_select_kernel(
    const float* __restrict__ emb, const float* __restrict__ scores,
    const int* __restrict__ topk_ptr, float* __restrict__ pooled,
    float* __restrict__ attn, int K, int D)
{
    __shared__ float s_sc[TKP_MAXK];
    __shared__ int   sel[TKP_MAXSEL];

    const int b = blockIdx.x;
    const int t = threadIdx.x;

    int k = topk_ptr[0];
    if (k > K) k = K;
    if (k > TKP_MAXSEL) k = TKP_MAXSEL;
    if (k < 1) k = 1;

    if (t < 64) {
        // ---- wave 0: load scores to LDS, then k argmax rounds, barrier-free
        for (int j = t; j < K; j += 64) s_sc[j] = scores[(size_t)b * K + j];
        for (int i = 0; i < k; ++i) {
            float bv = TKP_FLT_LOW;
            int   bi = 0x7fffffff;
            for (int j = t; j < K; j += 64) {
                float v = s_sc[j];
                if (v > bv) { bv = v; bi = j; }   // ascending j -> lower index wins ties
            }
            #pragma unroll
            for (int off = 32; off; off >>= 1) {
                float ov = __shfl_xor(bv, off, 64);
                int   oi = __shfl_xor(bi, off, 64);
                if (ov > bv || (ov == bv && oi < bi)) { bv = ov; bi = oi; }
            }
            // all lanes agree on (bv, bi)
            if (t == 0) { sel[i] = bi; s_sc[bi] = TKP_FLT_LOW; }
            // intra-wave LDS write->read: ordered by lgkmcnt, no barrier needed
        }
    } else {
        // ---- waves 1-3: zero the attn row concurrently
        for (int j = t - 64; j < K; j += 192) attn[(size_t)b * K + j] = 0.f;
    }
    __syncthreads();

    const float inv_k = 1.0f / (float)k;

    // scatter 1/k at selected indices (attn row already zeroed)
    for (int i = t; i < k; i += 256) attn[(size_t)b * K + sel[i]] = inv_k;

    // pooled: mean of k selected rows, float4-vectorized, coalesced over d
    const int D4 = D >> 2;
    const float4* __restrict__ emb4 = reinterpret_cast<const float4*>(emb);
    float4* __restrict__ pooled4 = reinterpret_cast<float4*>(pooled);
    for (int p = t; p < D4; p += 256) {
        float4 acc = make_float4(0.f, 0.f, 0.f, 0.f);
        for (int i = 0; i < k; ++i) {
            float4 v = emb4[((size_t)b * K + sel[i]) * D4 + p];
            acc.x += v.x; acc.y += v.y; acc.z += v.z; acc.w += v.w;
        }
        acc.x *= inv_k; acc.y *= inv_k; acc.z *= inv_k; acc.w *= inv_k;
        pooled4[(size_t)b * D4 + p] = acc;
    }
}

extern "C" void kernel_launch(void* const* d_in, const int* in_sizes, int n_in,
                              void* d_out, int out_size, void* d_ws, size_t ws_size,
                              hipStream_t stream) {
    const float* emb   = (const float*)d_in[0];
    const int*   mask  = (const int*)d_in[1];
    const float* w     = (const float*)d_in[2];
    const float* bias  = (const float*)d_in[3];
    const int*   topk  = (const int*)d_in[4];

    const int BK = in_sizes[1];           // B*K
    const int D  = in_sizes[0] / BK;      // 768
    const int B  = (out_size - BK) / D;   // out_size = B*D + B*K
    const int K  = BK / B;                // 512

    float* scores = (float*)d_ws;                    // B*K floats of scratch
    float* pooled = (float*)d_out;                   // (B, D)
    float* attn   = (float*)d_out + (size_t)B * D;   // (B, K)

    if (D == 768) {
        const int blocks1 = (BK + 15) / 16;          // 16 rows per block
        topkpool_scores_t<192><<<blocks1, 256, 0, stream>>>(emb, mask, w, bias, scores, BK);
    } else if ((D & 3) == 0 && D <= 4096) {
        // other mult-of-4 D: generic wave-per-row path
        topkpool_scores_gen<<<(BK + 3) / 4, 256, 0, stream>>>(emb, mask, w, bias, scores, BK, D);
    } else {
        topkpool_scores_gen<<<(BK + 3) / 4, 256, 0, stream>>>(emb, mask, w, bias, scores, BK, D);
    }
    topkpool_select_kernel<<<B, 256, 0, stream>>>(emb, scores, topk, pooled, attn, K, D);
}